// Round 2
// baseline (907.682 us; speedup 1.0000x reference)
//
#include <hip/hip_runtime.h>
#include <stdint.h>

typedef __attribute__((ext_vector_type(4))) float f32x4;
typedef __attribute__((ext_vector_type(8))) __bf16 bf16x8;
typedef __attribute__((ext_vector_type(4))) __bf16 bf16x4;

#define NB 2
#define NS 2048
#define ND 2048
#define NH 16
#define NHD 128
#define NM (NB*NS)      // 4096 rows
#define NQKV (3*ND)     // 6144

__device__ __forceinline__ short f2bf(float f) {
  union { float f; uint32_t u; } c; c.f = f;
  uint32_t r = (c.u + 0x7FFFu + ((c.u >> 16) & 1u)) >> 16;
  return (short)r;
}

__device__ __forceinline__ void gl_lds16(const short* g, short* l) {
  __builtin_amdgcn_global_load_lds(
      (const __attribute__((address_space(1))) void*)g,
      (__attribute__((address_space(3))) void*)l, 16, 0, 0);
}

// ---------------- fp32 -> bf16 elementwise ----------------
__global__ __launch_bounds__(256) void cvt_bf16_kernel(const float* __restrict__ in,
                                                       short* __restrict__ out, int n4) {
  int i = blockIdx.x * 256 + threadIdx.x;
  if (i >= n4) return;
  float4 v = ((const float4*)in)[i];
  short4 o;
  o.x = f2bf(v.x); o.y = f2bf(v.y); o.z = f2bf(v.z); o.w = f2bf(v.w);
  ((short4*)out)[i] = o;
}

// ---------------- fp32 [rows][cols] -> bf16 [cols][rows] ----------------
__global__ __launch_bounds__(256) void transpose_cvt_kernel(const float* __restrict__ in,
                                                            short* __restrict__ out,
                                                            int rows, int cols) {
  __shared__ float tile[64][65];
  const int tx = threadIdx.x, ty = threadIdx.y;
  const int r0 = blockIdx.y * 64, c0 = blockIdx.x * 64;
  for (int i = ty; i < 64; i += 4)
    tile[i][tx] = in[(size_t)(r0 + i) * cols + c0 + tx];
  __syncthreads();
  for (int i = ty; i < 64; i += 4)
    out[(size_t)(c0 + i) * rows + r0 + tx] = f2bf(tile[tx][i]);
}

// ---------------- bf16 GEMM: C = A[M][K] * Bt[N][K]^T, 128x128 tile ----------------
template<int EPI>
__global__ __launch_bounds__(256) void gemm_kernel(
    const short* __restrict__ A, const short* __restrict__ Bt, int K, int N,
    const float* __restrict__ bias,
    short* __restrict__ Qb, short* __restrict__ Kb, short* __restrict__ Vtb,
    const float* __restrict__ residual, float* __restrict__ out) {
  const int tid = threadIdx.x;
  const int w = tid >> 6, l = tid & 63;
  const int l15 = l & 15, l4 = l >> 4;
  const int wm = (w >> 1) * 64, wn = (w & 1) * 64;
  const int rowBase = blockIdx.y * 128, colBase = blockIdx.x * 128;

  __shared__ short As[2][128 * 32];
  __shared__ short Bs[2][128 * 32];

  f32x4 acc[4][4] = {};

  const int sRow = tid >> 2;          // 0..63
  const int sCol = (tid & 3) * 8;
  const short* gA0 = A + (size_t)(rowBase + sRow) * K + sCol;
  const short* gB0 = Bt + (size_t)(colBase + sRow) * K + sCol;
  const int ldsW = w * 512;           // shorts

  const int nk = K / 32;

#define STAGE(buf, k0) do {                                      \
    gl_lds16(gA0 + (k0),                 &As[buf][ldsW]);        \
    gl_lds16(gA0 + (size_t)64*K + (k0),  &As[buf][2048 + ldsW]); \
    gl_lds16(gB0 + (k0),                 &Bs[buf][ldsW]);        \
    gl_lds16(gB0 + (size_t)64*K + (k0),  &Bs[buf][2048 + ldsW]); \
  } while (0)

  STAGE(0, 0);
  __syncthreads();
  int cur = 0;
  for (int kt = 0; kt < nk; ++kt) {
    if (kt + 1 < nk) STAGE(cur ^ 1, (kt + 1) * 32);
    bf16x8 a[4], b[4];
#pragma unroll
    for (int i = 0; i < 4; ++i) {
      a[i] = *(const bf16x8*)&As[cur][(wm + i * 16 + l15) * 32 + l4 * 8];
      b[i] = *(const bf16x8*)&Bs[cur][(wn + i * 16 + l15) * 32 + l4 * 8];
    }
#pragma unroll
    for (int i = 0; i < 4; ++i)
#pragma unroll
      for (int j = 0; j < 4; ++j)
        acc[i][j] = __builtin_amdgcn_mfma_f32_16x16x32_bf16(a[i], b[j], acc[i][j], 0, 0, 0);
    __syncthreads();
    cur ^= 1;
  }
#undef STAGE

#pragma unroll
  for (int i = 0; i < 4; ++i) {
#pragma unroll
    for (int j = 0; j < 4; ++j) {
#pragma unroll
      for (int r = 0; r < 4; ++r) {
        const int row = rowBase + wm + i * 16 + l4 * 4 + r;
        const int col = colBase + wn + j * 16 + l15;
        float v = acc[i][j][r] + bias[col];
        if (EPI == 0) {
          const int h = col / 384;
          const int sub = col - h * 384;
          const int t = sub >> 7, hd = sub & 127;
          const int bb = row >> 11, s = row & 2047;
          const size_t bh = (size_t)bb * NH + h;
          if (t == 0)      Qb[(bh * NS + s) * NHD + hd] = f2bf(v * 0.08838834764831845f);
          else if (t == 1) Kb[(bh * NS + s) * NHD + hd] = f2bf(v);
          else             Vtb[(bh * NHD + hd) * NS + s] = f2bf(v);
        } else {
          const size_t idx = (size_t)row * N + col;
          out[idx] = v + residual[idx];
        }
      }
    }
  }
}

// ---------------- flash attention, swapped-QK^T ----------------
// flat grid: 1024 blocks; bh = flat>>5, qt bit-swizzled for causal load balance.
// 4 waves/block, each wave owns 16 q-rows (q = qw + l15), KVBLK = 64.
__global__ __launch_bounds__(256) void attn_kernel(
    const short* __restrict__ Qb, const short* __restrict__ Kb,
    const short* __restrict__ Vtb, const float* __restrict__ alibi,
    const int* __restrict__ amask, short* __restrict__ Ob) {
  const int tid = threadIdx.x;
  const int w = tid >> 6, l = tid & 63;
  const int l15 = l & 15, l4 = l >> 4;
  const int flat = blockIdx.x;
  const int bh = flat >> 5;
  const int inner = flat & 31;
  const int qt = ((inner & 3) << 3) | (inner >> 2);  // balance causal depth
  const int bb = bh >> 4, h = bh & 15;
  const int q0 = qt * 64;
  const int qw = q0 + w * 16;

  __shared__ float biasLds[NS];        // 8 KB: alibi + pad mask, shared by block
  __shared__ short Plds[4][16 * 64];   // 8 KB: per-wave P^T relayout buffer

  // bias[k] = mask[k] ? alibi[k] : -1e30 (per bh)
  {
    const float* abase = alibi + (size_t)bh * NS;
    const int* mbase = amask + (size_t)bb * NS;
    for (int i = tid; i < NS; i += 256)
      biasLds[i] = mbase[i] ? abase[i] : -1e30f;
  }
  __syncthreads();

  // Q as B-fragment: lane holds Q[q=qw+l15][hd = s*32 + l4*8 + 0..7] (pre-scaled)
  const short* qptr = Qb + ((size_t)bh * NS + qw + l15) * NHD + l4 * 8;
  bf16x8 qf[4];
#pragma unroll
  for (int s = 0; s < 4; ++s) qf[s] = *(const bf16x8*)(qptr + s * 32);

  f32x4 acc[8] = {};                   // O^T: hd = 16t + l4*4 + r, q = l15
  float mrun = -1e30f, lrun = 0.f;

  const short* kbase = Kb + (size_t)bh * NS * NHD;
  const short* vbase = Vtb + (size_t)bh * NHD * NS;
  const int nkt = (qw + 79) >> 6;      // tiles while k0 <= qw+15
  short* myP = &Plds[w][0];
  const int pswz = (l15 & 7) << 3;     // element XOR (= byte XOR (l15&7)<<4)
  const int qglob = qw + l15;

  for (int kt = 0; kt < nkt; ++kt) {
    const int k0 = kt << 6;

    // S^T = K_tile * Q^T : lane holds S^T[key = 16p + l4*4 + r][q = l15]
    f32x4 sT[4] = {};
#pragma unroll
    for (int p = 0; p < 4; ++p) {
      const short* kp = kbase + (size_t)(k0 + p * 16 + l15) * NHD + l4 * 8;
#pragma unroll
      for (int s = 0; s < 4; ++s) {
        bf16x8 kf = *(const bf16x8*)(kp + s * 32);
        sT[p] = __builtin_amdgcn_mfma_f32_16x16x32_bf16(kf, qf[s], sT[p], 0, 0, 0);
      }
    }

    const bool full = (k0 + 63 <= qw);   // tile entirely below diagonal for all lanes
    float pv[16];
    float tmax = -1e30f;
#pragma unroll
    for (int p = 0; p < 4; ++p) {
      const f32x4 bvec = *(const f32x4*)&biasLds[k0 + p * 16 + l4 * 4];
#pragma unroll
      for (int r = 0; r < 4; ++r) {
        float v = sT[p][r] + bvec[r];
        if (!full) {
          const int kg = k0 + p * 16 + l4 * 4 + r;
          v = (kg <= qglob) ? v : -1e30f;
        }
        pv[p * 4 + r] = v;
        tmax = fmaxf(tmax, v);
      }
    }
    // full row max: combine the 4 lane-groups holding this q's keys
    tmax = fmaxf(tmax, __shfl_xor(tmax, 16, 64));
    tmax = fmaxf(tmax, __shfl_xor(tmax, 32, 64));
    const float mnew = fmaxf(mrun, tmax);
    const float alpha = __expf(mrun - mnew);
    mrun = mnew;
    float psum = 0.f;
#pragma unroll
    for (int i = 0; i < 16; ++i) {
      pv[i] = __expf(pv[i] - mnew);
      psum += pv[i];
    }
    psum += __shfl_xor(psum, 16, 64);
    psum += __shfl_xor(psum, 32, 64);
    lrun = lrun * alpha + psum;
#pragma unroll
    for (int t = 0; t < 8; ++t)
#pragma unroll
      for (int r = 0; r < 4; ++r)
        acc[t][r] *= alpha;

    // P^T -> LDS (swizzled 8B packed writes): Plds[q][k] = P[q][k]
#pragma unroll
    for (int p = 0; p < 4; ++p) {
      bf16x4 pk = { (__bf16)pv[p * 4 + 0], (__bf16)pv[p * 4 + 1],
                    (__bf16)pv[p * 4 + 2], (__bf16)pv[p * 4 + 3] };
      const int col = p * 16 + l4 * 4;
      *(bf16x4*)&myP[(l15 << 6) + (col ^ pswz)] = pk;
    }
    asm volatile("s_waitcnt lgkmcnt(0)" ::: "memory");
    __builtin_amdgcn_sched_barrier(0);

    // O^T += V^T * P^T
#pragma unroll
    for (int c = 0; c < 2; ++c) {
      const bf16x8 pf = *(const bf16x8*)&myP[(l15 << 6) + ((c * 32 + l4 * 8) ^ pswz)];
      const short* vp = vbase + (size_t)l15 * NS + k0 + c * 32 + l4 * 8;
#pragma unroll
      for (int t = 0; t < 8; ++t) {
        bf16x8 vf = *(const bf16x8*)(vp + (size_t)t * 16 * NS);
        acc[t] = __builtin_amdgcn_mfma_f32_16x16x32_bf16(vf, pf, acc[t], 0, 0, 0);
      }
    }
  }

  const float inv = (lrun > 0.f) ? 1.0f / lrun : 0.f;
  short* obase = Ob + ((size_t)bb * NS + qw + l15) * ND + h * NHD + l4 * 4;
#pragma unroll
  for (int t = 0; t < 8; ++t) {
    bf16x4 o = { (__bf16)(acc[t][0] * inv), (__bf16)(acc[t][1] * inv),
                 (__bf16)(acc[t][2] * inv), (__bf16)(acc[t][3] * inv) };
    *(bf16x4*)&obase[t * 16] = o;
  }
}

extern "C" void kernel_launch(void* const* d_in, const int* in_sizes, int n_in,
                              void* d_out, int out_size, void* d_ws, size_t ws_size,
                              hipStream_t stream) {
  const float* hidden   = (const float*)d_in[0];
  const float* residual = (const float*)d_in[1];
  const float* alibi    = (const float*)d_in[2];
  const float* W_qkv    = (const float*)d_in[3];
  const float* b_qkv    = (const float*)d_in[4];
  const float* W_o      = (const float*)d_in[5];
  const float* b_o      = (const float*)d_in[6];
  const int*   amask    = (const int*)d_in[7];
  float* out = (float*)d_out;

  char* p = (char*)d_ws;
  short* Abuf  = (short*)p; p += (size_t)NM * ND * 2;
  short* WqkvT = (short*)p; p += (size_t)NQKV * ND * 2;
  short* WoT   = (short*)p; p += (size_t)ND * ND * 2;
  short* Qb    = (short*)p; p += (size_t)NB * NH * NS * NHD * 2;
  short* Kb    = (short*)p; p += (size_t)NB * NH * NS * NHD * 2;
  short* Vtb   = (short*)p; p += (size_t)NB * NH * NS * NHD * 2;
  short* Ob    = (short*)p; p += (size_t)NM * ND * 2;

  cvt_bf16_kernel<<<(NM * ND / 4) / 256, 256, 0, stream>>>(hidden, Abuf, NM * ND / 4);
  transpose_cvt_kernel<<<dim3(NQKV / 64, ND / 64), dim3(64, 4), 0, stream>>>(W_qkv, WqkvT, ND, NQKV);
  transpose_cvt_kernel<<<dim3(ND / 64, ND / 64), dim3(64, 4), 0, stream>>>(W_o, WoT, ND, ND);
  gemm_kernel<0><<<dim3(NQKV / 128, NM / 128), 256, 0, stream>>>(
      Abuf, WqkvT, ND, NQKV, b_qkv, Qb, Kb, Vtb, nullptr, nullptr);
  attn_kernel<<<dim3(NB * NH * 32), 256, 0, stream>>>(Qb, Kb, Vtb, alibi, amask, Ob);
  gemm_kernel<1><<<dim3(ND / 128, NM / 128), 256, 0, stream>>>(
      Ob, WoT, ND, ND, b_o, nullptr, nullptr, nullptr, residual, out);
}

// Round 3
// 469.682 us; speedup vs baseline: 1.9325x; 1.9325x over previous
//
#include <hip/hip_runtime.h>
#include <stdint.h>

typedef __attribute__((ext_vector_type(4))) float f32x4;
typedef __attribute__((ext_vector_type(8))) __bf16 bf16x8;
typedef __attribute__((ext_vector_type(4))) __bf16 bf16x4;

#define NB 2
#define NS 2048
#define ND 2048
#define NH 16
#define NHD 128
#define NM (NB*NS)      // 4096 rows
#define NQKV (3*ND)     // 6144

__device__ __forceinline__ short f2bf(float f) {
  union { float f; uint32_t u; } c; c.f = f;
  uint32_t r = (c.u + 0x7FFFu + ((c.u >> 16) & 1u)) >> 16;
  return (short)r;
}

__device__ __forceinline__ void gl_lds16(const short* g, short* l) {
  __builtin_amdgcn_global_load_lds(
      (const __attribute__((address_space(1))) void*)g,
      (__attribute__((address_space(3))) void*)l, 16, 0, 0);
}

// ---------------- fp32 -> bf16 elementwise ----------------
__global__ __launch_bounds__(256) void cvt_bf16_kernel(const float* __restrict__ in,
                                                       short* __restrict__ out, int n4) {
  int i = blockIdx.x * 256 + threadIdx.x;
  if (i >= n4) return;
  float4 v = ((const float4*)in)[i];
  short4 o;
  o.x = f2bf(v.x); o.y = f2bf(v.y); o.z = f2bf(v.z); o.w = f2bf(v.w);
  ((short4*)out)[i] = o;
}

// ---------------- fp32 [rows][cols] -> bf16 [cols][rows] ----------------
__global__ __launch_bounds__(256) void transpose_cvt_kernel(const float* __restrict__ in,
                                                            short* __restrict__ out,
                                                            int rows, int cols) {
  __shared__ float tile[64][65];
  const int tx = threadIdx.x, ty = threadIdx.y;
  const int r0 = blockIdx.y * 64, c0 = blockIdx.x * 64;
  for (int i = ty; i < 64; i += 4)
    tile[i][tx] = in[(size_t)(r0 + i) * cols + c0 + tx];
  __syncthreads();
  for (int i = ty; i < 64; i += 4)
    out[(size_t)(c0 + i) * rows + r0 + tx] = f2bf(tile[tx][i]);
}

// ---------------- bf16 GEMM: C = A[M][K] * Bt[N][K]^T, 128x128 tile ----------------
template<int EPI>
__global__ __launch_bounds__(256) void gemm_kernel(
    const short* __restrict__ A, const short* __restrict__ Bt, int K, int N,
    const float* __restrict__ bias,
    short* __restrict__ Qb, short* __restrict__ Kb, short* __restrict__ Vtb,
    const float* __restrict__ residual, float* __restrict__ out) {
  const int tid = threadIdx.x;
  const int w = tid >> 6, l = tid & 63;
  const int l15 = l & 15, l4 = l >> 4;
  const int wm = (w >> 1) * 64, wn = (w & 1) * 64;
  const int rowBase = blockIdx.y * 128, colBase = blockIdx.x * 128;

  __shared__ short As[2][128 * 32];
  __shared__ short Bs[2][128 * 32];

  f32x4 acc[4][4] = {};

  const int sRow = tid >> 2;          // 0..63
  const int sCol = (tid & 3) * 8;
  const short* gA0 = A + (size_t)(rowBase + sRow) * K + sCol;
  const short* gB0 = Bt + (size_t)(colBase + sRow) * K + sCol;
  const int ldsW = w * 512;           // shorts

  const int nk = K / 32;

#define STAGE(buf, k0) do {                                      \
    gl_lds16(gA0 + (k0),                 &As[buf][ldsW]);        \
    gl_lds16(gA0 + (size_t)64*K + (k0),  &As[buf][2048 + ldsW]); \
    gl_lds16(gB0 + (k0),                 &Bs[buf][ldsW]);        \
    gl_lds16(gB0 + (size_t)64*K + (k0),  &Bs[buf][2048 + ldsW]); \
  } while (0)

  STAGE(0, 0);
  __syncthreads();
  int cur = 0;
  for (int kt = 0; kt < nk; ++kt) {
    if (kt + 1 < nk) STAGE(cur ^ 1, (kt + 1) * 32);
    bf16x8 a[4], b[4];
#pragma unroll
    for (int i = 0; i < 4; ++i) {
      a[i] = *(const bf16x8*)&As[cur][(wm + i * 16 + l15) * 32 + l4 * 8];
      b[i] = *(const bf16x8*)&Bs[cur][(wn + i * 16 + l15) * 32 + l4 * 8];
    }
#pragma unroll
    for (int i = 0; i < 4; ++i)
#pragma unroll
      for (int j = 0; j < 4; ++j)
        acc[i][j] = __builtin_amdgcn_mfma_f32_16x16x32_bf16(a[i], b[j], acc[i][j], 0, 0, 0);
    __syncthreads();
    cur ^= 1;
  }
#undef STAGE

#pragma unroll
  for (int i = 0; i < 4; ++i) {
#pragma unroll
    for (int j = 0; j < 4; ++j) {
#pragma unroll
      for (int r = 0; r < 4; ++r) {
        const int row = rowBase + wm + i * 16 + l4 * 4 + r;
        const int col = colBase + wn + j * 16 + l15;
        float v = acc[i][j][r] + bias[col];
        if (EPI == 0) {
          const int h = col / 384;
          const int sub = col - h * 384;
          const int t = sub >> 7, hd = sub & 127;
          const int bb = row >> 11, s = row & 2047;
          const size_t bh = (size_t)bb * NH + h;
          if (t == 0)      Qb[(bh * NS + s) * NHD + hd] = f2bf(v * 0.08838834764831845f);
          else if (t == 1) Kb[(bh * NS + s) * NHD + hd] = f2bf(v);
          else             Vtb[(bh * NHD + hd) * NS + s] = f2bf(v);
        } else {
          const size_t idx = (size_t)row * N + col;
          out[idx] = v + residual[idx];
        }
      }
    }
  }
}

// ---------------- flash attention, swapped-QK^T ----------------
// flat grid: 1024 blocks. bh = flat&31 (XCD = flat%8 -> 4 bh per XCD L2).
// qt = (z<<3)|(z&1 ? 7-y : y), z=flat>>8, y=(flat>>5)&7: per-CU qt-sum constant.
// 4 waves/block, each wave owns 16 q-rows (q = qw + l15), KVBLK = 64.
__global__ __launch_bounds__(256, 2) void attn_kernel(
    const short* __restrict__ Qb, const short* __restrict__ Kb,
    const short* __restrict__ Vtb, const float* __restrict__ alibi,
    const int* __restrict__ amask, short* __restrict__ Ob) {
  const int tid = threadIdx.x;
  const int w = tid >> 6, l = tid & 63;
  const int l15 = l & 15, l4 = l >> 4;
  const int flat = blockIdx.x;
  const int bh = flat & 31;
  const int z = flat >> 8, y = (flat >> 5) & 7;
  const int qt = (z << 3) | ((z & 1) ? (7 - y) : y);
  const int bb = bh >> 4, h = bh & 15;
  const int q0 = qt * 64;
  const int qw = q0 + w * 16;

  __shared__ float biasLds[NS];        // 8 KB: alibi + pad mask, shared by block
  __shared__ short Plds[4][16 * 64];   // 8 KB: per-wave P^T relayout buffer

  {
    const float* abase = alibi + (size_t)bh * NS;
    const int* mbase = amask + (size_t)bb * NS;
    for (int i = tid; i < NS; i += 256)
      biasLds[i] = mbase[i] ? abase[i] : -1e30f;
  }
  __syncthreads();

  // Q as B-fragment: lane holds Q[q=qw+l15][hd = s*32 + l4*8 + 0..7] (pre-scaled)
  const short* qptr = Qb + ((size_t)bh * NS + qw + l15) * NHD + l4 * 8;
  bf16x8 qf[4];
#pragma unroll
  for (int s = 0; s < 4; ++s) qf[s] = *(const bf16x8*)(qptr + s * 32);

  f32x4 acc[8] = {};                   // O^T: hd = 16t + l4*4 + r, q = l15
  float mrun = -1e30f, lrun = 0.f;

  const short* kbase = Kb + (size_t)bh * NS * NHD;
  const short* vbase = Vtb + (size_t)bh * NHD * NS;
  const int nkt = (qw + 79) >> 6;      // tiles while k0 <= qw+15
  short* myP = &Plds[w][0];
  const int pswz = (l15 & 7) << 3;     // element XOR (= byte XOR (l15&7)<<4)
  const int qglob = qw + l15;

  for (int kt = 0; kt < nkt; ++kt) {
    const int k0 = kt << 6;

    // S^T = K_tile * Q^T : lane holds S^T[key = 16p + l4*4 + r][q = l15]
    f32x4 sT[4] = {};
#pragma unroll
    for (int p = 0; p < 4; ++p) {
      const short* kp = kbase + (size_t)(k0 + p * 16 + l15) * NHD + l4 * 8;
#pragma unroll
      for (int s = 0; s < 4; ++s) {
        bf16x8 kf = *(const bf16x8*)(kp + s * 32);
        sT[p] = __builtin_amdgcn_mfma_f32_16x16x32_bf16(kf, qf[s], sT[p], 0, 0, 0);
      }
    }

    // Prefetch V half 0 (keys k0..k0+31) while softmax runs.
    const short* vp = vbase + (size_t)l15 * NS + k0 + l4 * 8;
    bf16x8 vf0[8];
#pragma unroll
    for (int t = 0; t < 8; ++t)
      vf0[t] = *(const bf16x8*)(vp + (size_t)t * 16 * NS);

    const bool full = (k0 + 63 <= qw);   // tile entirely below diagonal
    float pv[16];
    float tmax = -1e30f;
#pragma unroll
    for (int p = 0; p < 4; ++p) {
      const f32x4 bvec = *(const f32x4*)&biasLds[k0 + p * 16 + l4 * 4];
#pragma unroll
      for (int r = 0; r < 4; ++r) {
        float v = sT[p][r] + bvec[r];
        if (!full) {
          const int kg = k0 + p * 16 + l4 * 4 + r;
          v = (kg <= qglob) ? v : -1e30f;
        }
        pv[p * 4 + r] = v;
        tmax = fmaxf(tmax, v);
      }
    }
    tmax = fmaxf(tmax, __shfl_xor(tmax, 16, 64));
    tmax = fmaxf(tmax, __shfl_xor(tmax, 32, 64));
    const float mnew = fmaxf(mrun, tmax);
    const float alpha = __expf(mrun - mnew);
    mrun = mnew;
    float psum = 0.f;
#pragma unroll
    for (int i = 0; i < 16; ++i) {
      pv[i] = __expf(pv[i] - mnew);
      psum += pv[i];
    }
    psum += __shfl_xor(psum, 16, 64);
    psum += __shfl_xor(psum, 32, 64);
    lrun = lrun * alpha + psum;
#pragma unroll
    for (int t = 0; t < 8; ++t)
#pragma unroll
      for (int r = 0; r < 4; ++r)
        acc[t][r] *= alpha;

    // P^T -> LDS (swizzled 8B packed writes): Plds[q][k] = P[q][k]
#pragma unroll
    for (int p = 0; p < 4; ++p) {
      bf16x4 pk = { (__bf16)pv[p * 4 + 0], (__bf16)pv[p * 4 + 1],
                    (__bf16)pv[p * 4 + 2], (__bf16)pv[p * 4 + 3] };
      const int col = p * 16 + l4 * 4;
      *(bf16x4*)&myP[(l15 << 6) + (col ^ pswz)] = pk;
    }
    asm volatile("s_waitcnt lgkmcnt(0)" ::: "memory");

    // O^T += V^T * P^T ; prefetch V half 1 under PV half 0.
    const bf16x8 pf0 = *(const bf16x8*)&myP[(l15 << 6) + ((l4 * 8) ^ pswz)];
    bf16x8 vf1[8];
#pragma unroll
    for (int t = 0; t < 8; ++t)
      vf1[t] = *(const bf16x8*)(vp + 32 + (size_t)t * 16 * NS);
#pragma unroll
    for (int t = 0; t < 8; ++t)
      acc[t] = __builtin_amdgcn_mfma_f32_16x16x32_bf16(vf0[t], pf0, acc[t], 0, 0, 0);
    const bf16x8 pf1 = *(const bf16x8*)&myP[(l15 << 6) + ((32 + l4 * 8) ^ pswz)];
#pragma unroll
    for (int t = 0; t < 8; ++t)
      acc[t] = __builtin_amdgcn_mfma_f32_16x16x32_bf16(vf1[t], pf1, acc[t], 0, 0, 0);
  }

  const float inv = (lrun > 0.f) ? 1.0f / lrun : 0.f;
  short* obase = Ob + ((size_t)bb * NS + qw + l15) * ND + h * NHD + l4 * 4;
#pragma unroll
  for (int t = 0; t < 8; ++t) {
    bf16x4 o = { (__bf16)(acc[t][0] * inv), (__bf16)(acc[t][1] * inv),
                 (__bf16)(acc[t][2] * inv), (__bf16)(acc[t][3] * inv) };
    *(bf16x4*)&obase[t * 16] = o;
  }
}

extern "C" void kernel_launch(void* const* d_in, const int* in_sizes, int n_in,
                              void* d_out, int out_size, void* d_ws, size_t ws_size,
                              hipStream_t stream) {
  const float* hidden   = (const float*)d_in[0];
  const float* residual = (const float*)d_in[1];
  const float* alibi    = (const float*)d_in[2];
  const float* W_qkv    = (const float*)d_in[3];
  const float* b_qkv    = (const float*)d_in[4];
  const float* W_o      = (const float*)d_in[5];
  const float* b_o      = (const float*)d_in[6];
  const int*   amask    = (const int*)d_in[7];
  float* out = (float*)d_out;

  char* p = (char*)d_ws;
  short* Abuf  = (short*)p; p += (size_t)NM * ND * 2;
  short* WqkvT = (short*)p; p += (size_t)NQKV * ND * 2;
  short* WoT   = (short*)p; p += (size_t)ND * ND * 2;
  short* Qb    = (short*)p; p += (size_t)NB * NH * NS * NHD * 2;
  short* Kb    = (short*)p; p += (size_t)NB * NH * NS * NHD * 2;
  short* Vtb   = (short*)p; p += (size_t)NB * NH * NS * NHD * 2;
  short* Ob    = (short*)p; p += (size_t)NM * ND * 2;

  cvt_bf16_kernel<<<(NM * ND / 4) / 256, 256, 0, stream>>>(hidden, Abuf, NM * ND / 4);
  transpose_cvt_kernel<<<dim3(NQKV / 64, ND / 64), dim3(64, 4), 0, stream>>>(W_qkv, WqkvT, ND, NQKV);
  transpose_cvt_kernel<<<dim3(ND / 64, ND / 64), dim3(64, 4), 0, stream>>>(W_o, WoT, ND, ND);
  gemm_kernel<0><<<dim3(NQKV / 128, NM / 128), 256, 0, stream>>>(
      Abuf, WqkvT, ND, NQKV, b_qkv, Qb, Kb, Vtb, nullptr, nullptr);
  attn_kernel<<<dim3(NB * NH * 32), 256, 0, stream>>>(Qb, Kb, Vtb, alibi, amask, Ob);
  gemm_kernel<1><<<dim3(ND / 128, NM / 128), 256, 0, stream>>>(
      Ob, WoT, ND, ND, b_o, nullptr, nullptr, nullptr, residual, out);
}

// Round 4
// 337.590 us; speedup vs baseline: 2.6887x; 1.3913x over previous
//
#include <hip/hip_runtime.h>
#include <stdint.h>

typedef __attribute__((ext_vector_type(4))) float f32x4;
typedef __attribute__((ext_vector_type(8))) __bf16 bf16x8;
typedef __attribute__((ext_vector_type(4))) __bf16 bf16x4;

#define NB 2
#define NS 2048
#define ND 2048
#define NH 16
#define NHD 128
#define NM (NB*NS)      // 4096 rows
#define NQKV (3*ND)     // 6144

__device__ __forceinline__ short f2bf(float f) {
  union { float f; uint32_t u; } c; c.f = f;
  uint32_t r = (c.u + 0x7FFFu + ((c.u >> 16) & 1u)) >> 16;
  return (short)r;
}

__device__ __forceinline__ void gl_lds16(const short* g, short* l) {
  __builtin_amdgcn_global_load_lds(
      (const __attribute__((address_space(1))) void*)g,
      (__attribute__((address_space(3))) void*)l, 16, 0, 0);
}

// ---------------- fp32 -> bf16 elementwise ----------------
__global__ __launch_bounds__(256) void cvt_bf16_kernel(const float* __restrict__ in,
                                                       short* __restrict__ out, int n4) {
  int i = blockIdx.x * 256 + threadIdx.x;
  if (i >= n4) return;
  float4 v = ((const float4*)in)[i];
  short4 o;
  o.x = f2bf(v.x); o.y = f2bf(v.y); o.z = f2bf(v.z); o.w = f2bf(v.w);
  ((short4*)out)[i] = o;
}

// ---------------- fp32 [rows][cols] -> bf16 [cols][rows] ----------------
__global__ __launch_bounds__(256) void transpose_cvt_kernel(const float* __restrict__ in,
                                                            short* __restrict__ out,
                                                            int rows, int cols) {
  __shared__ float tile[64][65];
  const int tx = threadIdx.x, ty = threadIdx.y;
  const int r0 = blockIdx.y * 64, c0 = blockIdx.x * 64;
  for (int i = ty; i < 64; i += 4)
    tile[i][tx] = in[(size_t)(r0 + i) * cols + c0 + tx];
  __syncthreads();
  for (int i = ty; i < 64; i += 4)
    out[(size_t)(c0 + i) * rows + r0 + tx] = f2bf(tile[tx][i]);
}

// ---------------- bf16 GEMM: C = A[M][K] * Bt[N][K]^T, 128x128 tile ----------------
template<int EPI>
__global__ __launch_bounds__(256) void gemm_kernel(
    const short* __restrict__ A, const short* __restrict__ Bt, int K, int N,
    const float* __restrict__ bias,
    short* __restrict__ Qb, short* __restrict__ Kb, short* __restrict__ Vtb,
    const float* __restrict__ residual, float* __restrict__ out) {
  const int tid = threadIdx.x;
  const int w = tid >> 6, l = tid & 63;
  const int l15 = l & 15, l4 = l >> 4;
  const int wm = (w >> 1) * 64, wn = (w & 1) * 64;
  const int rowBase = blockIdx.y * 128, colBase = blockIdx.x * 128;

  __shared__ short As[2][128 * 32];
  __shared__ short Bs[2][128 * 32];

  f32x4 acc[4][4] = {};

  const int sRow = tid >> 2;
  const int sCol = (tid & 3) * 8;
  const short* gA0 = A + (size_t)(rowBase + sRow) * K + sCol;
  const short* gB0 = Bt + (size_t)(colBase + sRow) * K + sCol;
  const int ldsW = w * 512;

  const int nk = K / 32;

#define STAGE(buf, k0) do {                                      \
    gl_lds16(gA0 + (k0),                 &As[buf][ldsW]);        \
    gl_lds16(gA0 + (size_t)64*K + (k0),  &As[buf][2048 + ldsW]); \
    gl_lds16(gB0 + (k0),                 &Bs[buf][ldsW]);        \
    gl_lds16(gB0 + (size_t)64*K + (k0),  &Bs[buf][2048 + ldsW]); \
  } while (0)

  STAGE(0, 0);
  __syncthreads();
  int cur = 0;
  for (int kt = 0; kt < nk; ++kt) {
    if (kt + 1 < nk) STAGE(cur ^ 1, (kt + 1) * 32);
    bf16x8 a[4], b[4];
#pragma unroll
    for (int i = 0; i < 4; ++i) {
      a[i] = *(const bf16x8*)&As[cur][(wm + i * 16 + l15) * 32 + l4 * 8];
      b[i] = *(const bf16x8*)&Bs[cur][(wn + i * 16 + l15) * 32 + l4 * 8];
    }
#pragma unroll
    for (int i = 0; i < 4; ++i)
#pragma unroll
      for (int j = 0; j < 4; ++j)
        acc[i][j] = __builtin_amdgcn_mfma_f32_16x16x32_bf16(a[i], b[j], acc[i][j], 0, 0, 0);
    __syncthreads();
    cur ^= 1;
  }
#undef STAGE

#pragma unroll
  for (int i = 0; i < 4; ++i) {
#pragma unroll
    for (int j = 0; j < 4; ++j) {
#pragma unroll
      for (int r = 0; r < 4; ++r) {
        const int row = rowBase + wm + i * 16 + l4 * 4 + r;
        const int col = colBase + wn + j * 16 + l15;
        float v = acc[i][j][r] + bias[col];
        if (EPI == 0) {
          const int h = col / 384;
          const int sub = col - h * 384;
          const int t = sub >> 7, hd = sub & 127;
          const int bb = row >> 11, s = row & 2047;
          const size_t bh = (size_t)bb * NH + h;
          if (t == 0)      Qb[(bh * NS + s) * NHD + hd] = f2bf(v * 0.08838834764831845f);
          else if (t == 1) Kb[(bh * NS + s) * NHD + hd] = f2bf(v);
          else             Vtb[(bh * NHD + hd) * NS + s] = f2bf(v);
        } else {
          const size_t idx = (size_t)row * N + col;
          out[idx] = v + residual[idx];
        }
      }
    }
  }
}

// ---------------- flash attention v4: QBLK=32/wave, K in LDS (swizzled) ----------------
// grid: 512 blocks. bh = flat&31 (XCD=flat%8 consistent with bh%8).
// qt = z ? 15-y : y  (z=flat>>8, y=(flat>>5)&7): per-CU pair {y,15-y}.
// 4 waves x 32 q-rows = 128 q/block. KVBLK=64. NT = 2*qt+2 tiles (uniform).
__global__ __launch_bounds__(256, 2) void attn_kernel(
    const short* __restrict__ Qb, const short* __restrict__ Kb,
    const short* __restrict__ Vtb, const float* __restrict__ alibi,
    const int* __restrict__ amask, short* __restrict__ Ob) {
  const int tid = threadIdx.x;
  const int w = tid >> 6, l = tid & 63;
  const int l15 = l & 15, l4 = l >> 4;
  const int flat = blockIdx.x;
  const int bh = flat & 31;
  const int y = (flat >> 5) & 7, z = flat >> 8;
  const int qt = z ? (15 - y) : y;
  const int bb = bh >> 4, h = bh & 15;
  const int q0 = qt * 128;
  const int qw = q0 + w * 32;
  const int NT = 2 * qt + 2;

  __shared__ float biasLds[NS];          //  8 KB
  __shared__ short Ks[2][64 * 128];      // 32 KB dbuf K tile, XOR-swizzled
  __shared__ short Plds[4][32 * 64];     // 16 KB per-wave P^T

  {
    const float* abase = alibi + (size_t)bh * NS;
    const int* mbase = amask + (size_t)bb * NS;
    for (int i = tid; i < NS; i += 256)
      biasLds[i] = mbase[i] ? abase[i] : -1e30f;
  }

  const short* kbase = Kb + (size_t)bh * NS * NHD;
  const short* vbase = Vtb + (size_t)bh * NHD * NS;

  // stage K tile kt0 -> Ks[buf]; wave w covers rows 16w..16w+15.
  // LDS linear dest; global source pre-swizzled: LDS byte L holds K[row][(L&255)^((row&7)<<4)]
#define KSTAGE(buf, kt0) do {                                                  \
    _Pragma("unroll")                                                          \
    for (int i_ = 0; i_ < 4; ++i_) {                                           \
      const int Lb_ = w * 4096 + i_ * 1024 + l * 16;                           \
      const int row_ = Lb_ >> 8;                                               \
      const int X_ = (Lb_ & 255) ^ ((row_ & 7) << 4);                          \
      gl_lds16((const short*)((const char*)kbase + (size_t)((kt0) * 64 + row_) * 256 + X_), \
               (short*)((char*)&Ks[buf][0] + (w * 4096 + i_ * 1024)));         \
    }                                                                          \
  } while (0)

  // Q as B-frag: qf[c][s]: lane holds Q[qw+16c+l15][s*32+l4*8 ..+7]
  const short* qp = Qb + ((size_t)bh * NS + qw + l15) * NHD + l4 * 8;
  bf16x8 qf[2][4];
#pragma unroll
  for (int c = 0; c < 2; ++c)
#pragma unroll
    for (int s = 0; s < 4; ++s)
      qf[c][s] = *(const bf16x8*)(qp + c * 16 * NHD + s * 32);

  f32x4 acc[2][8] = {};
  float mrun[2] = {-1e30f, -1e30f}, lrun[2] = {0.f, 0.f};

  short* myP = &Plds[w][0];
  const int pswzB = (l15 & 7) << 4;       // byte XOR for P LDS
  const int qg0 = qw + l15, qg1 = qw + 16 + l15;

  KSTAGE(0, 0);
  __syncthreads();
  int cur = 0;

  for (int t = 0; t < NT; ++t) {
    const int k0 = t << 6;
    if (t + 1 < NT) KSTAGE(cur ^ 1, t + 1);

    if (k0 <= qw + 31) {
      // ---- QK^T from LDS-K (swizzled read) ----
      f32x4 sT[2][4] = {};
      __builtin_amdgcn_s_setprio(1);
#pragma unroll
      for (int p = 0; p < 4; ++p) {
        const int lrow = p * 16 + l15;
#pragma unroll
        for (int s = 0; s < 4; ++s) {
          const int lbyte = (lrow << 8) + ((s * 64 + l4 * 16) ^ ((lrow & 7) << 4));
          const bf16x8 kf = *(const bf16x8*)((const char*)&Ks[cur][0] + lbyte);
          sT[0][p] = __builtin_amdgcn_mfma_f32_16x16x32_bf16(kf, qf[0][s], sT[0][p], 0, 0, 0);
          sT[1][p] = __builtin_amdgcn_mfma_f32_16x16x32_bf16(kf, qf[1][s], sT[1][p], 0, 0, 0);
        }
      }
      __builtin_amdgcn_s_setprio(0);

      // ---- V half 0 prefetch (keys k0..k0+31) ----
      const short* vp = vbase + (size_t)l15 * NS + k0 + l4 * 8;
      bf16x8 vA[8];
#pragma unroll
      for (int t8 = 0; t8 < 8; ++t8)
        vA[t8] = *(const bf16x8*)(vp + (size_t)t8 * 16 * NS);

      // ---- softmax (per q-column) ----
      const bool full = (k0 + 63 <= qw);
      float pv[2][16];
      float tmax[2] = {-1e30f, -1e30f};
#pragma unroll
      for (int p = 0; p < 4; ++p) {
        const f32x4 bvec = *(const f32x4*)&biasLds[k0 + p * 16 + l4 * 4];
#pragma unroll
        for (int r = 0; r < 4; ++r) {
          const int kg = k0 + p * 16 + l4 * 4 + r;
          float v0 = sT[0][p][r] + bvec[r];
          float v1 = sT[1][p][r] + bvec[r];
          if (!full) {
            v0 = (kg <= qg0) ? v0 : -1e30f;
            v1 = (kg <= qg1) ? v1 : -1e30f;
          }
          pv[0][p * 4 + r] = v0; pv[1][p * 4 + r] = v1;
          tmax[0] = fmaxf(tmax[0], v0);
          tmax[1] = fmaxf(tmax[1], v1);
        }
      }
      float alpha[2], inv_unused;
#pragma unroll
      for (int c = 0; c < 2; ++c) {
        tmax[c] = fmaxf(tmax[c], __shfl_xor(tmax[c], 16, 64));
        tmax[c] = fmaxf(tmax[c], __shfl_xor(tmax[c], 32, 64));
        const float mnew = fmaxf(mrun[c], tmax[c]);
        alpha[c] = __expf(mrun[c] - mnew);
        mrun[c] = mnew;
        float psum = 0.f;
#pragma unroll
        for (int i = 0; i < 16; ++i) {
          pv[c][i] = __expf(pv[c][i] - mnew);
          psum += pv[c][i];
        }
        psum += __shfl_xor(psum, 16, 64);
        psum += __shfl_xor(psum, 32, 64);
        lrun[c] = lrun[c] * alpha[c] + psum;
#pragma unroll
        for (int t8 = 0; t8 < 8; ++t8)
#pragma unroll
          for (int r = 0; r < 4; ++r)
            acc[c][t8][r] *= alpha[c];
      }

      // ---- P^T -> LDS (swizzled 8B stores) ----
#pragma unroll
      for (int c = 0; c < 2; ++c)
#pragma unroll
        for (int p = 0; p < 4; ++p) {
          bf16x4 pk = { (__bf16)pv[c][p * 4 + 0], (__bf16)pv[c][p * 4 + 1],
                        (__bf16)pv[c][p * 4 + 2], (__bf16)pv[c][p * 4 + 3] };
          const int byteoff = ((16 * c + l15) << 7) + (((p * 16 + l4 * 4) << 1) ^ pswzB);
          *(bf16x4*)((char*)myP + byteoff) = pk;
        }
      asm volatile("s_waitcnt lgkmcnt(0)" ::: "memory");

      // ---- PV: O^T += V^T * P^T (half 0 then half 1) ----
      bf16x8 pfA[2], pfB[2];
#pragma unroll
      for (int c = 0; c < 2; ++c)
        pfA[c] = *(const bf16x8*)((const char*)myP + ((16 * c + l15) << 7) + ((l4 * 16) ^ pswzB));
      bf16x8 vB[8];
#pragma unroll
      for (int t8 = 0; t8 < 8; ++t8)
        vB[t8] = *(const bf16x8*)(vp + 32 + (size_t)t8 * 16 * NS);
      __builtin_amdgcn_s_setprio(1);
#pragma unroll
      for (int t8 = 0; t8 < 8; ++t8) {
        acc[0][t8] = __builtin_amdgcn_mfma_f32_16x16x32_bf16(vA[t8], pfA[0], acc[0][t8], 0, 0, 0);
        acc[1][t8] = __builtin_amdgcn_mfma_f32_16x16x32_bf16(vA[t8], pfA[1], acc[1][t8], 0, 0, 0);
      }
      __builtin_amdgcn_s_setprio(0);
#pragma unroll
      for (int c = 0; c < 2; ++c)
        pfB[c] = *(const bf16x8*)((const char*)myP + ((16 * c + l15) << 7) + ((64 + l4 * 16) ^ pswzB));
      __builtin_amdgcn_s_setprio(1);
#pragma unroll
      for (int t8 = 0; t8 < 8; ++t8) {
        acc[0][t8] = __builtin_amdgcn_mfma_f32_16x16x32_bf16(vB[t8], pfB[0], acc[0][t8], 0, 0, 0);
        acc[1][t8] = __builtin_amdgcn_mfma_f32_16x16x32_bf16(vB[t8], pfB[1], acc[1][t8], 0, 0, 0);
      }
      __builtin_amdgcn_s_setprio(0);
    }

    __syncthreads();
    cur ^= 1;
  }
#undef KSTAGE

#pragma unroll
  for (int c = 0; c < 2; ++c) {
    const float inv = (lrun[c] > 0.f) ? 1.0f / lrun[c] : 0.f;
    short* obase = Ob + ((size_t)bb * NS + qw + 16 * c + l15) * ND + h * NHD + l4 * 4;
#pragma unroll
    for (int t8 = 0; t8 < 8; ++t8) {
      bf16x4 o = { (__bf16)(acc[c][t8][0] * inv), (__bf16)(acc[c][t8][1] * inv),
                   (__bf16)(acc[c][t8][2] * inv), (__bf16)(acc[c][t8][3] * inv) };
      *(bf16x4*)&obase[t8 * 16] = o;
    }
  }
}

extern "C" void kernel_launch(void* const* d_in, const int* in_sizes, int n_in,
                              void* d_out, int out_size, void* d_ws, size_t ws_size,
                              hipStream_t stream) {
  const float* hidden   = (const float*)d_in[0];
  const float* residual = (const float*)d_in[1];
  const float* alibi    = (const float*)d_in[2];
  const float* W_qkv    = (const float*)d_in[3];
  const float* b_qkv    = (const float*)d_in[4];
  const float* W_o      = (const float*)d_in[5];
  const float* b_o      = (const float*)d_in[6];
  const int*   amask    = (const int*)d_in[7];
  float* out = (float*)d_out;

  char* p = (char*)d_ws;
  short* Abuf  = (short*)p; p += (size_t)NM * ND * 2;
  short* WqkvT = (short*)p; p += (size_t)NQKV * ND * 2;
  short* WoT   = (short*)p; p += (size_t)ND * ND * 2;
  short* Qb    = (short*)p; p += (size_t)NB * NH * NS * NHD * 2;
  short* Kb    = (short*)p; p += (size_t)NB * NH * NS * NHD * 2;
  short* Vtb   = (short*)p; p += (size_t)NB * NH * NS * NHD * 2;
  short* Ob    = (short*)p; p += (size_t)NM * ND * 2;

  cvt_bf16_kernel<<<(NM * ND / 4) / 256, 256, 0, stream>>>(hidden, Abuf, NM * ND / 4);
  transpose_cvt_kernel<<<dim3(NQKV / 64, ND / 64), dim3(64, 4), 0, stream>>>(W_qkv, WqkvT, ND, NQKV);
  transpose_cvt_kernel<<<dim3(ND / 64, ND / 64), dim3(64, 4), 0, stream>>>(W_o, WoT, ND, ND);
  gemm_kernel<0><<<dim3(NQKV / 128, NM / 128), 256, 0, stream>>>(
      Abuf, WqkvT, ND, NQKV, b_qkv, Qb, Kb, Vtb, nullptr, nullptr);
  attn_kernel<<<dim3(512), 256, 0, stream>>>(Qb, Kb, Vtb, alibi, amask, Ob);
  gemm_kernel<1><<<dim3(ND / 128, NM / 128), 256, 0, stream>>>(
      Ob, WoT, ND, ND, b_o, nullptr, nullptr, nullptr, residual, out);
}